// Round 5
// baseline (153.541 us; speedup 1.0000x reference)
//
#include <hip/hip_runtime.h>
#include <hip/hip_bf16.h>
#include <math.h>

#define D_DIM   4096
#define B_ROWS  4096
#define K_CODES 256
#define MARGIN  3.0      // |approx d2 - exact d2| <= ~1.5 worst-case; 3.0 window
#define KS      8        // K-split
#define KSLICE  (D_DIM / KS)   // 512
#define BK      64
#define NITER   (KSLICE / BK)  // 8
#define MT      32             // M rows per block

// output layout (f32 elements)
#define IDX_OFF   (B_ROWS * D_DIM)                 // 16777216
#define PROBS_OFF (IDX_OFF + B_ROWS)               // 16781312
#define LOSS_OFF  (PROBS_OFF + B_ROWS * K_CODES)   // 17829888

typedef __bf16 bf16x8 __attribute__((ext_vector_type(8)));
typedef float  f32x16 __attribute__((ext_vector_type(16)));

// ws: part[KS][4096][256] f32 (32 MB) | cbsw (2 MB) | cc[256] f64 | xxp[KS][4096] f32
// cbsw layout: [panel = k/64][q = (k/8)&7][code][off = k&7] ushort
#define PART_ELEMS ((size_t)KS * B_ROWS * K_CODES)

static __device__ inline unsigned short f2bf(float f) {
    __hip_bfloat16 h = __float2bfloat16(f);
    return *reinterpret_cast<unsigned short*>(&h);
}

// ---------------------------------------------------------------------------
// prep_cb: one wave per codebook row. Writes swizzled bf16 codebook + cc.
// ---------------------------------------------------------------------------
__global__ __launch_bounds__(64) void prep_cb(const float* __restrict__ cb,
                                              unsigned short* __restrict__ cbsw,
                                              double* __restrict__ cc) {
    const int lane = threadIdx.x & 63;
    const int k = blockIdx.x;                            // code 0..255
    const float4* row4 = (const float4*)(cb + (size_t)k * D_DIM);
    double a0 = 0.0, a1 = 0.0, a2 = 0.0, a3 = 0.0;
#pragma unroll
    for (int i = 0; i < 16; ++i) {
        float4 v = row4[i * 64 + lane];
        a0 += (double)v.x * v.x; a1 += (double)v.y * v.y;
        a2 += (double)v.z * v.z; a3 += (double)v.w * v.w;
        ushort4 h;
        h.x = f2bf(v.x); h.y = f2bf(v.y); h.z = f2bf(v.z); h.w = f2bf(v.w);
        const int c = (i * 64 + lane) * 4;           // global k of this chunk
        const int panel = c >> 6, q = (c >> 3) & 7, off = c & 7;
        *(ushort4*)&cbsw[(((size_t)panel * 8 + q) * K_CODES + k) * 8 + off] = h;
    }
    double s = (a0 + a1) + (a2 + a3);
    for (int off = 32; off; off >>= 1) s += __shfl_xor(s, off);
    if (lane == 0) cc[k] = s;
}

// ---------------------------------------------------------------------------
// gemm v4: B straight to VGPRs (no B LDS). 32x256 tile, grid (128,8)=1024
// blocks = 4 blocks/CU, LDS = As only (2 x 4 KB). Each wave's B fragment is a
// disjoint contiguous 512 B run of cbsw -> coalesced global_load_dwordx4,
// L2-resident, pipelined one s-step ahead. Barriers drain lgkm only; global
// loads stay in flight across them (compiler inserts use-waits).
// ---------------------------------------------------------------------------
__global__ __launch_bounds__(256, 3) void gemm(const float* __restrict__ x,
                                               const unsigned short* __restrict__ cbsw,
                                               float* __restrict__ part,
                                               float* __restrict__ xxp) {
    __shared__ unsigned short As[2][8 * MT * 8];        // [p][q][row32][8]  2 x 4 KB
    const int t = threadIdx.x;
    const int lane = t & 63, w = t >> 6;
    const int h = lane >> 5, mr = lane & 31;
    const int m0 = blockIdx.x * MT;
    const int ks = blockIdx.y;
    const int k0 = ks * KSLICE;

    // A staging: thread t -> row t>>3, k-chunks acg and acg+32 of each BK tile
    const int arow = t >> 3, acg = 4 * (t & 7);
    const float* ag = x + (size_t)(m0 + arow) * D_DIM + k0 + acg;
    const int aw0 = (((acg >> 3)    ) * MT + arow) * 8 + (acg & 7);
    const int aw1 = (((acg >> 3) + 4) * MT + arow) * 8 + (acg & 7);
    // B frags: for (it, s, h): cbsw[ks*NITER*16384 + it*16384 + (2s+h)*2048 + (w*64+mr)*8]
    const unsigned short* bbase = cbsw + (size_t)(ks * NITER) * 16384
                                + h * 2048 + (w * 64 + mr) * 8;

    f32x16 acc0, acc1;
#pragma unroll
    for (int i = 0; i < 16; ++i) { acc0[i] = 0.f; acc1[i] = 0.f; }
    float sq = 0.f;

    // ---- prologue: A(0) -> As[0], A(1) -> regs, B(0,s=0) -> regs ----
    float4 p0 = *(const float4*)(ag);
    float4 p1 = *(const float4*)(ag + 32);
    float4 c0 = *(const float4*)(ag + BK);
    float4 c1 = *(const float4*)(ag + BK + 32);
    bf16x8 bc0 = *(const bf16x8*)(bbase);
    bf16x8 bc1 = *(const bf16x8*)(bbase + 256);
    {
        ushort4 h0, h1;
        h0.x = f2bf(p0.x); h0.y = f2bf(p0.y); h0.z = f2bf(p0.z); h0.w = f2bf(p0.w);
        h1.x = f2bf(p1.x); h1.y = f2bf(p1.y); h1.z = f2bf(p1.z); h1.w = f2bf(p1.w);
        *(ushort4*)&As[0][aw0] = h0;
        *(ushort4*)&As[0][aw1] = h1;
        sq += p0.x*p0.x + p0.y*p0.y + p0.z*p0.z + p0.w*p0.w
            + p1.x*p1.x + p1.y*p1.y + p1.z*p1.z + p1.w*p1.w;
    }
    asm volatile("s_waitcnt lgkmcnt(0)" ::: "memory");
    __builtin_amdgcn_s_barrier();
    __builtin_amdgcn_sched_barrier(0);

    // ---- main loop ----
#pragma unroll
    for (int it = 0; it < NITER; ++it) {
        const int p = it & 1, pn = p ^ 1;

        // stage A(it+1) into buffer pn (safe: pn's readers finished at the
        // barrier ending iter it-1)
        if (it + 1 < NITER) {
            ushort4 h0, h1;
            h0.x = f2bf(c0.x); h0.y = f2bf(c0.y); h0.z = f2bf(c0.z); h0.w = f2bf(c0.w);
            h1.x = f2bf(c1.x); h1.y = f2bf(c1.y); h1.z = f2bf(c1.z); h1.w = f2bf(c1.w);
            *(ushort4*)&As[pn][aw0] = h0;
            *(ushort4*)&As[pn][aw1] = h1;
            sq += c0.x*c0.x + c0.y*c0.y + c0.z*c0.z + c0.w*c0.w
                + c1.x*c1.x + c1.y*c1.y + c1.z*c1.z + c1.w*c1.w;
        }
        // issue A(it+2) prefetch (clamped)
        const int t2 = (it + 2 < NITER) ? (it + 2) * BK : 0;
        float4 n0 = *(const float4*)(ag + t2);
        float4 n1 = *(const float4*)(ag + t2 + 32);

        // MFMA over 4 s-steps; B pipelined one step ahead (global->reg)
        __builtin_amdgcn_s_setprio(1);
#pragma unroll
        for (int s = 0; s < 4; ++s) {
            const int nit = (s < 3) ? it : ((it + 1 < NITER) ? it + 1 : 0);
            const int ns  = (s < 3) ? s + 1 : 0;
            const unsigned short* np = bbase + (size_t)nit * 16384 + ns * 4096;
            bf16x8 bn0 = *(const bf16x8*)(np);
            bf16x8 bn1 = *(const bf16x8*)(np + 256);
            bf16x8 af = *(const bf16x8*)&As[p][((2 * s + h) * MT + mr) * 8];
            acc0 = __builtin_amdgcn_mfma_f32_32x32x16_bf16(af, bc0, acc0, 0, 0, 0);
            acc1 = __builtin_amdgcn_mfma_f32_32x32x16_bf16(af, bc1, acc1, 0, 0, 0);
            bc0 = bn0; bc1 = bn1;
        }
        __builtin_amdgcn_s_setprio(0);

        // publish As[pn]; only lgkm drained — global loads ride across
        asm volatile("s_waitcnt lgkmcnt(0)" ::: "memory");
        __builtin_amdgcn_s_barrier();
        __builtin_amdgcn_sched_barrier(0);

        c0 = n0; c1 = n1;
    }

    // xx partials: reduce over the 8 threads sharing a row (lanes t&7)
    sq += __shfl_xor(sq, 1); sq += __shfl_xor(sq, 2); sq += __shfl_xor(sq, 4);
    if ((t & 7) == 0) xxp[(size_t)ks * B_ROWS + m0 + arow] = sq;

    float* dst = part + ((size_t)ks * B_ROWS + m0) * K_CODES + w * 64;
#pragma unroll
    for (int r = 0; r < 16; ++r) {
        const int rowit = (r & 3) + 8 * (r >> 2) + 4 * h;
        dst[(size_t)rowit * K_CODES + mr]      = acc0[r];
        dst[(size_t)rowit * K_CODES + 32 + mr] = acc1[r];
    }
}

// ---------------------------------------------------------------------------
// finish: wave-per-row. d2 from partials (f64), butterfly max, margin
// candidates; single candidate -> done; else exact f64 refinement (rare).
// ---------------------------------------------------------------------------
__global__ __launch_bounds__(256) void finish(const float* __restrict__ x,
                                              const float* __restrict__ cb,
                                              const float* __restrict__ part,
                                              const double* __restrict__ cc,
                                              const float* __restrict__ xxp,
                                              float* __restrict__ out) {
    const int lane = threadIdx.x & 63;
    const int row = blockIdx.x * 4 + (threadIdx.x >> 6);

    double xx = 0.0;
#pragma unroll
    for (int s = 0; s < KS; ++s) xx += (double)xxp[(size_t)s * B_ROWS + row];
    float4 p[KS];
#pragma unroll
    for (int s = 0; s < KS; ++s)
        p[s] = ((const float4*)(part + ((size_t)s * B_ROWS + row) * K_CODES))[lane];
    double v[4];
    {
        double s0 = 0.0, s1 = 0.0, s2 = 0.0, s3 = 0.0;
#pragma unroll
        for (int s = 0; s < KS; ++s) {
            s0 += (double)p[s].x; s1 += (double)p[s].y;
            s2 += (double)p[s].z; s3 += (double)p[s].w;
        }
        v[0] = xx + cc[4 * lane + 0] - 2.0 * s0;
        v[1] = xx + cc[4 * lane + 1] - 2.0 * s1;
        v[2] = xx + cc[4 * lane + 2] - 2.0 * s2;
        v[3] = xx + cc[4 * lane + 3] - 2.0 * s3;
    }

    double mx = fmax(fmax(v[0], v[1]), fmax(v[2], v[3]));
    for (int off = 32; off; off >>= 1) mx = fmax(mx, __shfl_xor(mx, off));
    const double thr = mx - MARGIN;

    unsigned long long b[4];
#pragma unroll
    for (int j = 0; j < 4; ++j) b[j] = __ballot(v[j] >= thr);
    const int total = __popcll(b[0]) + __popcll(b[1]) + __popcll(b[2]) + __popcll(b[3]);

    int bestk = 0; double best;
    if (total == 1) {
        best = mx;   // lone candidate IS the max; error bound guarantees argmax
#pragma unroll
        for (int j = 0; j < 4; ++j)
            if (b[j]) bestk = 4 * (int)__builtin_ctzll(b[j]) + j;
    } else {
        const float4* xrow4 = (const float4*)(x + (size_t)row * D_DIM);
        int flags = 0;
#pragma unroll
        for (int j = 0; j < 4; ++j) if (v[j] >= thr) flags |= 1 << j;
        unsigned long long cand = __ballot(flags != 0);
        best = -1.0e300;
        while (cand) {
            const int lsrc = __builtin_ctzll(cand);
            cand &= cand - 1;
            const int f = __shfl(flags, lsrc);
            for (int j = 0; j < 4; ++j) {
                if (!((f >> j) & 1)) continue;
                const int k = 4 * lsrc + j;
                const float4* crow4 = (const float4*)(cb + (size_t)k * D_DIM);
                double a0 = 0.0, a1 = 0.0, a2 = 0.0, a3 = 0.0;
#pragma unroll
                for (int i = 0; i < 16; ++i) {
                    float4 xa = xrow4[i * 64 + lane];
                    float4 ca = crow4[i * 64 + lane];
                    a0 += (double)xa.x * ca.x; a1 += (double)xa.y * ca.y;
                    a2 += (double)xa.z * ca.z; a3 += (double)xa.w * ca.w;
                }
                double s = (a0 + a1) + (a2 + a3);
                for (int off = 32; off; off >>= 1) s += __shfl_xor(s, off);
                const double d2e = xx + cc[k] - 2.0 * s;    // identical across lanes
                if (d2e > best) { best = d2e; bestk = k; }  // ascending k, strict >
            }
        }
    }

    if (lane == 0) {
        out[IDX_OFF + row]  = (float)bestk;
        out[LOSS_OFF + row] = (float)(1.25 * best / (double)D_DIM);
    }
    float4 z = make_float4(0.f, 0.f, 0.f, 0.f);
    ((float4*)(out + PROBS_OFF + (size_t)row * K_CODES))[lane] = z;
    const float4* src = (const float4*)(cb + (size_t)bestk * D_DIM);
    float4* dst = (float4*)(out + (size_t)row * D_DIM);
#pragma unroll
    for (int i = 0; i < 16; ++i) dst[i * 64 + lane] = src[i * 64 + lane];
}

// ---------------------------------------------------------------------------
extern "C" void kernel_launch(void* const* d_in, const int* in_sizes, int n_in,
                              void* d_out, int out_size, void* d_ws, size_t ws_size,
                              hipStream_t stream) {
    const float* x  = (const float*)d_in[0];
    const float* cb = (const float*)d_in[1];
    float* out = (float*)d_out;

    float*          part = (float*)d_ws;
    unsigned short* cbsw = (unsigned short*)((char*)d_ws + PART_ELEMS * sizeof(float));
    double*         cc   = (double*)((char*)cbsw + (size_t)K_CODES * D_DIM * sizeof(unsigned short));
    float*          xxp  = (float*)(cc + K_CODES);

    hipLaunchKernelGGL(prep_cb, dim3(256),     dim3(64),  0, stream, cb, cbsw, cc);
    hipLaunchKernelGGL(gemm,    dim3(128, KS), dim3(256), 0, stream, x, cbsw, part, xxp);
    hipLaunchKernelGGL(finish,  dim3(1024),    dim3(256), 0, stream, x, cb, part, cc, xxp, out);
}